// Round 1
// baseline (704.557 us; speedup 1.0000x reference)
//
#include <hip/hip_runtime.h>

#define Bb 1024
#define Ss 512
#define Ee 128
#define Hh 256
#define Vv 128
#define Cc 18

typedef __attribute__((ext_vector_type(8))) short short8;
typedef __attribute__((ext_vector_type(4))) short short4v;
typedef __attribute__((ext_vector_type(4))) float f32x4;

__device__ __forceinline__ unsigned short f2bf(float f) {
  union { float f; unsigned u; } v; v.f = f;
  return (unsigned short)((v.u + 0x7FFFu + ((v.u >> 16) & 1u)) >> 16);
}

__device__ __forceinline__ f32x4 mfma_bf16_16x16x32(short8 a, short8 b, f32x4 c) {
  return __builtin_amdgcn_mfma_f32_16x16x32_bf16(a, b, c, 0, 0, 0);
}

// ---------------- Kernel 1: T[v][j] = emb[v]·W_ih[j] + b_ih[j] + b_hh[j] ----------------
__global__ void prep_T(const float* __restrict__ emb, const float* __restrict__ W_ih,
                       const float* __restrict__ b_ih, const float* __restrict__ b_hh,
                       float* __restrict__ T) {
  __shared__ float elds[Ee];
  const int v = blockIdx.x, j = threadIdx.x;
  if (j < Ee) elds[j] = emb[v * Ee + j];
  __syncthreads();
  float s = b_ih[j] + b_hh[j];
  const float* wr = W_ih + j * Ee;
#pragma unroll 8
  for (int e = 0; e < Ee; e += 4) {
    f32x4 w = *(const f32x4*)(wr + e);
    f32x4 x = *(const f32x4*)(elds + e);
    s += w.x * x.x + w.y * x.y + w.z * x.z + w.w * x.w;
  }
  T[v * Hh + j] = s;
}

// ---------------- Kernel 2: the recurrence ----------------
// 64 blocks x 256 threads (4 waves). Block owns 16 batch rows.
// Transposed MFMA: D[j][r] = sum_k W[j][k] * h[r][k].
//   A-operand = W_hh tile (bf16, resident in VGPRs: 4 mt x 8 kt frags per wave)
//   B-operand = h^T from LDS (bf16, XOR-swizzled, 8 x ds_read_b128 per step)
//   C/D: batch row r = lane&15, j = j0 + mt*16 + (lane>>4)*4 + q  (4 consecutive j per frag)
__global__ __launch_bounds__(256, 1)
void rnn_kernel(const int* __restrict__ x_in, const int* __restrict__ x_len,
                const float* __restrict__ W_hh, const float* __restrict__ T,
                float* __restrict__ y) {
  __shared__ short h_buf[16 * 256];  // bf16 bits, row stride 512B, XOR-swizzled

  const int tid  = threadIdx.x;
  const int lane = tid & 63;
  const int wave = tid >> 6;
  const int l15  = lane & 15;
  const int g    = lane >> 4;        // 0..3
  const int j0   = wave * 64;        // wave's 64-column slice of H
  const int grow = blockIdx.x * 16;  // first batch row of this block
  const int r    = l15;              // this lane's batch row (0..15)

  // ---- one-time: load W_hh fragments into registers (A operand) ----
  short8 wfrag[4][8];
#pragma unroll
  for (int mt = 0; mt < 4; ++mt) {
    const float* wrow = W_hh + (j0 + mt * 16 + l15) * Hh;
#pragma unroll
    for (int kt = 0; kt < 8; ++kt) {
      const float* wp = wrow + kt * 32 + g * 8;
      f32x4 a = *(const f32x4*)(wp);
      f32x4 b = *(const f32x4*)(wp + 4);
      short8 f;
      f[0] = (short)f2bf(a.x); f[1] = (short)f2bf(a.y);
      f[2] = (short)f2bf(a.z); f[3] = (short)f2bf(a.w);
      f[4] = (short)f2bf(b.x); f[5] = (short)f2bf(b.y);
      f[6] = (short)f2bf(b.z); f[7] = (short)f2bf(b.w);
      wfrag[mt][kt] = f;
    }
  }

  const int mylen = x_len[grow + r];
  int maxlen = 1;
#pragma unroll
  for (int i = 0; i < 16; ++i) maxlen = max(maxlen, x_len[grow + i]);

  // zero h_0
  for (int i = tid; i < 16 * 256; i += 256) h_buf[i] = 0;

  // ---- T-gather software pipeline (prefetch one step ahead) ----
  const int xbase = (grow + r) * Ss;
  int xv_cur = x_in[xbase];
  int xv_nxt = x_in[xbase + 1 < xbase + Ss ? xbase + 1 : xbase] - x_in[xbase] ? 0 : 0; // placeholder, fixed below
  xv_nxt = x_in[xbase + ((1 < Ss) ? 1 : 0)];
  f32x4 tcur[4], tnxt[4];
#pragma unroll
  for (int mt = 0; mt < 4; ++mt)
    tcur[mt] = *(const f32x4*)(T + xv_cur * Hh + j0 + mt * 16 + g * 4);

  const int swz  = (r & 7) << 4;
  const int rowb = r * 512;
  __syncthreads();

  for (int t = 0; t < maxlen; ++t) {
    // read h_t fragments (B operand), swizzled
    short8 hfrag[8];
#pragma unroll
    for (int kt = 0; kt < 8; ++kt) {
      const int off = rowb + ((kt * 64 + g * 16) ^ swz);
      hfrag[kt] = *(const short8*)((const char*)h_buf + off);
    }

    // prefetch next step's T rows and the x two steps ahead (overlaps MFMA)
#pragma unroll
    for (int mt = 0; mt < 4; ++mt)
      tnxt[mt] = *(const f32x4*)(T + xv_nxt * Hh + j0 + mt * 16 + g * 4);
    const int xv_nn = x_in[xbase + min(t + 2, Ss - 1)];

    f32x4 acc[4];
#pragma unroll
    for (int mt = 0; mt < 4; ++mt) acc[mt] = tcur[mt];
#pragma unroll
    for (int kt = 0; kt < 8; ++kt) {
#pragma unroll
      for (int mt = 0; mt < 4; ++mt)
        acc[mt] = mfma_bf16_16x16x32(wfrag[mt][kt], hfrag[kt], acc[mt]);
    }

    __syncthreads();  // all waves' reads of h_t complete before overwrite

    const bool emit = (t == mylen - 1);
#pragma unroll
    for (int mt = 0; mt < 4; ++mt) {
      float hq[4];
#pragma unroll
      for (int q = 0; q < 4; ++q) {
        float xx = acc[mt][q];
        xx = fminf(fmaxf(xx, -12.f), 12.f);
        float e2 = __expf(2.f * xx);
        hq[q] = (e2 - 1.f) / (e2 + 1.f);
      }
      if (emit) {
        f32x4 o = {hq[0], hq[1], hq[2], hq[3]};
        *(f32x4*)(y + (grow + r) * Hh + j0 + mt * 16 + g * 4) = o;
      }
      short4v pk;
      pk[0] = (short)f2bf(hq[0]); pk[1] = (short)f2bf(hq[1]);
      pk[2] = (short)f2bf(hq[2]); pk[3] = (short)f2bf(hq[3]);
      const int off = rowb + (((j0 + mt * 16 + g * 4) * 2) ^ swz);
      *(short4v*)((char*)h_buf + off) = pk;
    }

    xv_cur = xv_nxt; xv_nxt = xv_nn;
#pragma unroll
    for (int mt = 0; mt < 4; ++mt) tcur[mt] = tnxt[mt];
    __syncthreads();  // h_{t+1} visible for next iteration
  }
}

// ---------------- Kernel 3: fc1 (relu) + fc2 ----------------
// 256 blocks x 256 threads; block owns 4 batch rows.
__global__ void fc_kernel(const float* __restrict__ y, const float* __restrict__ fc1_w,
                          const float* __restrict__ fc1_b, const float* __restrict__ fc2_w,
                          const float* __restrict__ fc2_b, float* __restrict__ out) {
  __shared__ float ylds[4][Hh];
  __shared__ float zlds[4][Hh];
  const int tid = threadIdx.x;
  const int r0  = blockIdx.x * 4;
  for (int i = tid; i < 4 * Hh; i += 256) ylds[i >> 8][i & 255] = y[r0 * Hh + i];
  __syncthreads();

  {  // fc1: thread j computes z[r][j], r=0..3
    const int j = tid;
    float a0 = fc1_b[j], a1 = a0, a2 = a0, a3 = a0;
    const float* wr = fc1_w + j * Hh;
    for (int k = 0; k < Hh; k += 4) {
      f32x4 w  = *(const f32x4*)(wr + k);
      f32x4 p0 = *(const f32x4*)(&ylds[0][k]);
      f32x4 p1 = *(const f32x4*)(&ylds[1][k]);
      f32x4 p2 = *(const f32x4*)(&ylds[2][k]);
      f32x4 p3 = *(const f32x4*)(&ylds[3][k]);
      a0 += w.x * p0.x + w.y * p0.y + w.z * p0.z + w.w * p0.w;
      a1 += w.x * p1.x + w.y * p1.y + w.z * p1.z + w.w * p1.w;
      a2 += w.x * p2.x + w.y * p2.y + w.z * p2.z + w.w * p2.w;
      a3 += w.x * p3.x + w.y * p3.y + w.z * p3.z + w.w * p3.w;
    }
    zlds[0][j] = fmaxf(a0, 0.f);
    zlds[1][j] = fmaxf(a1, 0.f);
    zlds[2][j] = fmaxf(a2, 0.f);
    zlds[3][j] = fmaxf(a3, 0.f);
  }
  __syncthreads();

  if (tid < 4 * Cc) {  // fc2: 72 outputs
    const int rr = tid / Cc, c = tid % Cc;
    float s = fc2_b[c];
    const float* wr = fc2_w + c * Hh;
    for (int k = 0; k < Hh; k += 4) {
      f32x4 w = *(const f32x4*)(wr + k);
      f32x4 z = *(const f32x4*)(&zlds[rr][k]);
      s += w.x * z.x + w.y * z.y + w.z * z.z + w.w * z.w;
    }
    out[(r0 + rr) * Cc + c] = s;
  }
}

extern "C" void kernel_launch(void* const* d_in, const int* in_sizes, int n_in,
                              void* d_out, int out_size, void* d_ws, size_t ws_size,
                              hipStream_t stream) {
  const int*   x_in  = (const int*)d_in[0];
  const int*   x_len = (const int*)d_in[1];
  const float* emb   = (const float*)d_in[2];
  const float* W_ih  = (const float*)d_in[3];
  const float* W_hh  = (const float*)d_in[4];
  const float* b_ih  = (const float*)d_in[5];
  const float* b_hh  = (const float*)d_in[6];
  const float* fc1_w = (const float*)d_in[7];
  const float* fc1_b = (const float*)d_in[8];
  const float* fc2_w = (const float*)d_in[9];
  const float* fc2_b = (const float*)d_in[10];
  float* out = (float*)d_out;

  float* T = (float*)d_ws;     // 128*256 f32 = 128 KB
  float* y = T + Vv * Hh;      // 1024*256 f32 = 1 MB

  prep_T<<<Vv, Hh, 0, stream>>>(emb, W_ih, b_ih, b_hh, T);
  rnn_kernel<<<Bb / 16, 256, 0, stream>>>(x_in, x_len, W_hh, T, y);
  fc_kernel<<<Bb / 4, 256, 0, stream>>>(y, fc1_w, fc1_b, fc2_w, fc2_b, out);
}

// Round 2
// 548.751 us; speedup vs baseline: 1.2839x; 1.2839x over previous
//
#include <hip/hip_runtime.h>

#define Bb 1024
#define Ss 512
#define Ee 128
#define Hh 256
#define Vv 128
#define Cc 18

typedef __attribute__((ext_vector_type(8))) short short8;
typedef __attribute__((ext_vector_type(4))) short short4v;
typedef __attribute__((ext_vector_type(4))) float f32x4;

__device__ __forceinline__ unsigned short f2bf(float f) {
  union { float f; unsigned u; } v; v.f = f;
  return (unsigned short)((v.u + 0x7FFFu + ((v.u >> 16) & 1u)) >> 16);
}

__device__ __forceinline__ f32x4 mfma_bf16_16x16x32(short8 a, short8 b, f32x4 c) {
  return __builtin_amdgcn_mfma_f32_16x16x32_bf16(a, b, c, 0, 0, 0);
}

// fast tanh: 1 - 2/(e^{2x}+1).  exp->inf gives +1, exp->0 gives -1; no clamp needed.
__device__ __forceinline__ float fast_tanh(float x) {
  float e2 = __expf(2.0f * x);
  return 1.0f - 2.0f * __builtin_amdgcn_rcpf(e2 + 1.0f);
}

// Load a 64-col slice of a [256][256] f32 row-major matrix as bf16 A-fragments.
// wfrag[mt][kt] holds rows j0+mt*16+l15, cols kt*32+g*8 .. +7 (16x16x32 A layout).
__device__ __forceinline__ void load_wfrags(const float* __restrict__ W, int j0, int l15, int g,
                                            short8 wfrag[4][8]) {
#pragma unroll
  for (int mt = 0; mt < 4; ++mt) {
    const float* wrow = W + (j0 + mt * 16 + l15) * Hh;
#pragma unroll
    for (int kt = 0; kt < 8; ++kt) {
      const float* wp = wrow + kt * 32 + g * 8;
      f32x4 a = *(const f32x4*)(wp);
      f32x4 b = *(const f32x4*)(wp + 4);
      short8 f;
      f[0] = (short)f2bf(a.x); f[1] = (short)f2bf(a.y);
      f[2] = (short)f2bf(a.z); f[3] = (short)f2bf(a.w);
      f[4] = (short)f2bf(b.x); f[5] = (short)f2bf(b.y);
      f[6] = (short)f2bf(b.z); f[7] = (short)f2bf(b.w);
      wfrag[mt][kt] = f;
    }
  }
}

// ---------------- Kernel 1: T[v][j] = emb[v]·W_ih[j] + b_ih[j] + b_hh[j] ----------------
__global__ void prep_T(const float* __restrict__ emb, const float* __restrict__ W_ih,
                       const float* __restrict__ b_ih, const float* __restrict__ b_hh,
                       float* __restrict__ T) {
  __shared__ float elds[Ee];
  const int v = blockIdx.x, j = threadIdx.x;
  if (j < Ee) elds[j] = emb[v * Ee + j];
  __syncthreads();
  float s = b_ih[j] + b_hh[j];
  const float* wr = W_ih + j * Ee;
#pragma unroll 8
  for (int e = 0; e < Ee; e += 4) {
    f32x4 w = *(const f32x4*)(wr + e);
    f32x4 x = *(const f32x4*)(elds + e);
    s += w.x * x.x + w.y * x.y + w.z * x.z + w.w * x.w;
  }
  T[v * Hh + j] = s;
}

// ---------------- Kernel 2: recurrence + fused FC head ----------------
// 64 blocks x 256 threads (4 waves), block owns 16 batch rows.
// Transposed MFMA: D[j][r] = sum_k W[j][k] * h[r][k].
// LDS layout (57344 B):
//   [0,16384)      h double buffer: 2 x [16 rows][512 B] bf16, XOR-swizzled
//   [16384,49152)  x tokens [16][512] int  (aliased by z f32 [16][256] after the loop)
//   [49152,57344)  y bf16 [16 rows][512 B], same swizzle (captured at emit)
__global__ __launch_bounds__(256, 1)
void rnn_fused(const int* __restrict__ x_in, const int* __restrict__ x_len,
               const float* __restrict__ W_hh, const float* __restrict__ T,
               const float* __restrict__ fc1_w, const float* __restrict__ fc1_b,
               const float* __restrict__ fc2_w, const float* __restrict__ fc2_b,
               float* __restrict__ out) {
  __shared__ __align__(16) char smem[57344];
  short* h0   = (short*)smem;
  int*   x_ld = (int*)(smem + 16384);
  float* z_ld = (float*)(smem + 16384);  // alias of x after the time loop
  char*  y_bf = smem + 49152;

  const int tid  = threadIdx.x;
  const int lane = tid & 63;
  const int wave = tid >> 6;
  const int l15  = lane & 15;
  const int g    = lane >> 4;        // 0..3
  const int j0   = wave * 64;
  const int grow = blockIdx.x * 16;
  const int r    = l15;              // this lane's batch row
  const int swz  = (r & 7) << 4;
  const int rowb = r * 512;

  // W_hh fragments resident in VGPRs
  short8 wfrag[4][8];
  load_wfrags(W_hh, j0, l15, g, wfrag);

  const int mylen = x_len[grow + r];
  int maxlen = 1;
#pragma unroll
  for (int i = 0; i < 16; ++i) maxlen = max(maxlen, x_len[grow + i]);

  // stage x (coalesced) + zero h buffer 0
  for (int i = tid; i < 16 * Ss; i += 256) x_ld[i] = x_in[grow * Ss + i];
  for (int i = tid; i < 16 * 256; i += 256) h0[i] = 0;
  __syncthreads();

  // precomputed LDS byte offsets
  int roff[8], woff[4];
#pragma unroll
  for (int kt = 0; kt < 8; ++kt) roff[kt] = rowb + ((kt * 64 + g * 16) ^ swz);
#pragma unroll
  for (int mt = 0; mt < 4; ++mt) woff[mt] = rowb + (((j0 + mt * 16 + g * 4) * 2) ^ swz);

  // prologue of the T-gather pipeline
  int xv_cur = x_ld[r * Ss];          // token t=0
  int xv_nxt = x_ld[r * Ss + 1];      // token t=1
  f32x4 tcur[4], tnxt[4];
#pragma unroll
  for (int mt = 0; mt < 4; ++mt)
    tcur[mt] = *(const f32x4*)(T + xv_cur * Hh + j0 + mt * 16 + g * 4);
  (void)xv_cur;

  const f32x4 zero4 = {0.f, 0.f, 0.f, 0.f};

  for (int t = 0; t < maxlen; ++t) {
    const char* hc = smem + ((t & 1) ? 8192 : 0);      // read h_t
    char*       hn = smem + ((t & 1) ? 0 : 8192);      // write h_{t+1}

    // issue next step's T gather FIRST (whole step to complete before the drain)
#pragma unroll
    for (int mt = 0; mt < 4; ++mt)
      tnxt[mt] = *(const f32x4*)(T + xv_nxt * Hh + j0 + mt * 16 + g * 4);
    const int xv_n2 = x_ld[r * Ss + min(t + 2, Ss - 1)];

    // h_t B-fragments
    short8 hf[8];
#pragma unroll
    for (int kt = 0; kt < 8; ++kt) hf[kt] = *(const short8*)(hc + roff[kt]);

    // 8 independent MFMA chains of depth 4
    f32x4 acc[4], acc2[4];
#pragma unroll
    for (int mt = 0; mt < 4; ++mt) { acc[mt] = tcur[mt]; acc2[mt] = zero4; }
#pragma unroll
    for (int kt = 0; kt < 4; ++kt) {
#pragma unroll
      for (int mt = 0; mt < 4; ++mt)
        acc[mt] = mfma_bf16_16x16x32(wfrag[mt][kt], hf[kt], acc[mt]);
    }
#pragma unroll
    for (int kt = 4; kt < 8; ++kt) {
#pragma unroll
      for (int mt = 0; mt < 4; ++mt)
        acc2[mt] = mfma_bf16_16x16x32(wfrag[mt][kt], hf[kt], acc2[mt]);
    }

    const bool emit = (t == mylen - 1);
#pragma unroll
    for (int mt = 0; mt < 4; ++mt) {
      f32x4 s = acc[mt];
      s.x += acc2[mt].x; s.y += acc2[mt].y; s.z += acc2[mt].z; s.w += acc2[mt].w;
      short4v pk;
      pk[0] = (short)f2bf(fast_tanh(s.x));
      pk[1] = (short)f2bf(fast_tanh(s.y));
      pk[2] = (short)f2bf(fast_tanh(s.z));
      pk[3] = (short)f2bf(fast_tanh(s.w));
      *(short4v*)(hn + woff[mt]) = pk;
      if (emit) *(short4v*)(y_bf + woff[mt]) = pk;   // capture y row in bf16
    }

    // rotate pipeline
#pragma unroll
    for (int mt = 0; mt < 4; ++mt) tcur[mt] = tnxt[mt];
    xv_nxt = xv_n2;
    __syncthreads();  // single barrier: h_{t+1} visible, T prefetch long done
  }

  // ---------------- fused FC head ----------------
  // fc1: z[j][r] = relu( fc1_b[j] + sum_k fc1_w[j][k] * y[r][k] ) — same MFMA structure
  short8 ffrag[4][8];
  load_wfrags(fc1_w, j0, l15, g, ffrag);
  f32x4 fb[4];
#pragma unroll
  for (int mt = 0; mt < 4; ++mt)
    fb[mt] = *(const f32x4*)(fc1_b + j0 + mt * 16 + g * 4);

  short8 yf[8];
#pragma unroll
  for (int kt = 0; kt < 8; ++kt) yf[kt] = *(const short8*)(y_bf + roff[kt]);

  f32x4 acc[4], acc2[4];
#pragma unroll
  for (int mt = 0; mt < 4; ++mt) { acc[mt] = fb[mt]; acc2[mt] = zero4; }
#pragma unroll
  for (int kt = 0; kt < 4; ++kt)
#pragma unroll
    for (int mt = 0; mt < 4; ++mt)
      acc[mt] = mfma_bf16_16x16x32(ffrag[mt][kt], yf[kt], acc[mt]);
#pragma unroll
  for (int kt = 4; kt < 8; ++kt)
#pragma unroll
    for (int mt = 0; mt < 4; ++mt)
      acc2[mt] = mfma_bf16_16x16x32(ffrag[mt][kt], yf[kt], acc2[mt]);

  __syncthreads();  // x_ld reads are over; safe to alias as z_ld
#pragma unroll
  for (int mt = 0; mt < 4; ++mt) {
    f32x4 z;
    z.x = fmaxf(acc[mt].x + acc2[mt].x, 0.f);
    z.y = fmaxf(acc[mt].y + acc2[mt].y, 0.f);
    z.z = fmaxf(acc[mt].z + acc2[mt].z, 0.f);
    z.w = fmaxf(acc[mt].w + acc2[mt].w, 0.f);
    *(f32x4*)(z_ld + r * 256 + j0 + mt * 16 + g * 4) = z;
  }
  __syncthreads();

  // fc2: 16 rows x 18 classes, scalar dots from LDS
  for (int idx = tid; idx < 16 * Cc; idx += 256) {
    const int rr = idx / Cc, c = idx % Cc;
    float s = fc2_b[c];
    const float* wr2 = fc2_w + c * Hh;
    const float* zr  = z_ld + rr * 256;
#pragma unroll 4
    for (int k = 0; k < Hh; k += 4) {
      f32x4 w = *(const f32x4*)(wr2 + k);
      f32x4 z = *(const f32x4*)(zr + k);
      s += w.x * z.x + w.y * z.y + w.z * z.z + w.w * z.w;
    }
    out[(grow + rr) * Cc + c] = s;
  }
}

extern "C" void kernel_launch(void* const* d_in, const int* in_sizes, int n_in,
                              void* d_out, int out_size, void* d_ws, size_t ws_size,
                              hipStream_t stream) {
  const int*   x_in  = (const int*)d_in[0];
  const int*   x_len = (const int*)d_in[1];
  const float* emb   = (const float*)d_in[2];
  const float* W_ih  = (const float*)d_in[3];
  const float* W_hh  = (const float*)d_in[4];
  const float* b_ih  = (const float*)d_in[5];
  const float* b_hh  = (const float*)d_in[6];
  const float* fc1_w = (const float*)d_in[7];
  const float* fc1_b = (const float*)d_in[8];
  const float* fc2_w = (const float*)d_in[9];
  const float* fc2_b = (const float*)d_in[10];
  float* out = (float*)d_out;

  float* T = (float*)d_ws;  // 128*256 f32 = 128 KB

  prep_T<<<Vv, Hh, 0, stream>>>(emb, W_ih, b_ih, b_hh, T);
  rnn_fused<<<Bb / 16, 256, 0, stream>>>(x_in, x_len, W_hh, T,
                                         fc1_w, fc1_b, fc2_w, fc2_b, out);
}